// Round 18
// baseline (52.791 us; speedup 1.0000x reference)
//
#include <hip/hip_runtime.h>
#include <math.h>

#define NQ 14
#define DEPTH 6
#define BLOCK 512
#define TS 528u       // bytes per 16x16 f16 tile: 512 data + 16 pad (132 dwords = 4 mod 32)
#define BUFSZ 33792u  // 64 * TS

typedef _Float16 h16;
typedef h16 h4 __attribute__((ext_vector_type(4)));
typedef float f4 __attribute__((ext_vector_type(4)));

// WAR barrier: no waitcnt (prior ds_reads already consumed by MFMA); does NOT
// drain vmcnt -> per-layer global gate loads stay in flight.
#define BAR_WAR() asm volatile("s_barrier" ::: "memory")
// Publish barrier: drain LDS writes only (lgkmcnt), not vmcnt.
#define BAR_PUB() asm volatile("s_waitcnt lgkmcnt(0)\n\ts_barrier" ::: "memory")

// ============ pre-kernel: constants -> d_ws ============
// BmG[24][256] h16 at ws+0 (12288 B); wtab[88] float at ws+12288.
__global__ __launch_bounds__(512, 1) void prep_kernel(
    const float* __restrict__ theta, const float* __restrict__ head_w,
    h16* __restrict__ BmG, float* __restrict__ wtab)
{
  __shared__ float2 gtab[DEPTH * NQ];
  const int t = threadIdx.x;
  if (t < DEPTH * NQ) {
    int d = t / NQ, bit = t - d * NQ;
    float hg = 0.5f * theta[d * NQ + (13 - bit)];
    gtab[t] = make_float2(cosf(hg), sinf(hg));
  }
  if (t < 88) {
    int o, v; float s = 0.f;
    if (t < 32) { o = t >> 4; v = t & 15;
      #pragma unroll
      for (int i = 0; i < 4; ++i) s += ((v>>i)&1) ? -head_w[o*NQ+i] : head_w[o*NQ+i];
    } else if (t < 64) { o = (t-32) >> 4; v = t & 15;
      #pragma unroll
      for (int i = 0; i < 4; ++i) s += ((v>>i)&1) ? -head_w[o*NQ+8+i] : head_w[o*NQ+8+i];
    } else if (t < 72) { o = (t-64) >> 2; v = t & 3;
      s = ((v&1)?-head_w[o*NQ+4]:head_w[o*NQ+4]) + ((v&2)?-head_w[o*NQ+5]:head_w[o*NQ+5]);
    } else if (t < 80) { o = (t-72) >> 2; v = t & 3;
      s = ((v&1)?-head_w[o*NQ+6]:head_w[o*NQ+6]) + ((v&2)?-head_w[o*NQ+7]:head_w[o*NQ+7]);
    } else { o = (t-80) >> 2; v = t & 3;
      s = ((v&1)?-head_w[o*NQ+12]:head_w[o*NQ+12]) + ((v&2)?-head_w[o*NQ+13]:head_w[o*NQ+13]);
    }
    wtab[t] = s;
  }
  __syncthreads();
  // Bm: 24 x 16 x 16 (arithmetic = rounds 5-17, CZ signs baked)
  #pragma unroll
  for (int i = 0; i < 12; ++i) {
    int e = t + (i << 9);
    int pid = e >> 8, n = (e >> 4) & 15, k = e & 15;
    int d = pid >> 2, p = pid & 3;
    float val;
    if (p < 3) {
      val = 1.f;
      #pragma unroll
      for (int j = 0; j < 4; ++j) {
        float2 g = gtab[d * NQ + 4 * p + j];
        val *= ((n >> j) & 1) ? (((k >> j) & 1) ? g.x : g.y)
                              : (((k >> j) & 1) ? -g.y : g.x);
      }
      if (d >= 1) {
        int s = ((k & (k >> 1)) ^ ((k >> 1) & (k >> 2)) ^ ((k >> 2) & (k >> 3))) & 1;
        if (s) val = -val;
        if ((n & 1) && (k & 8)) val = -val;    // cross-pair CZ sign
      }
    } else {          // g3grp = [12,13,6,7]: G12 x G13 x I x I
      if ((((n ^ k) >> 2) & 3) != 0) val = 0.f;
      else {
        float2 gA = gtab[d * NQ + 12], gB = gtab[d * NQ + 13];
        float f0 = (n & 1) ? ((k & 1) ? gA.x : gA.y) : ((k & 1) ? -gA.y : gA.x);
        float f1 = ((n >> 1) & 1) ? (((k >> 1) & 1) ? gB.x : gB.y)
                                  : (((k >> 1) & 1) ? -gB.y : gB.x);
        val = f0 * f1;
        if (d >= 1 && (k & (k >> 1) & 1)) val = -val;    // intra pair (12,13)
      }
    }
    BmG[pid * 256 + n * 16 + k] = (h16)val;
  }
}

// ============ main kernel ============
// ROUND-18: FUSED re+im — one block per batch item, two state buffers (bufR,
// bufI) sharing every barrier, address, gate fragment and weight table. Halves
// barrier crossings per unit work (46->23), doubles MFMA chains per interval
// (16 independent), deletes atomics + out-zeroing (direct store). 512 blocks =
// 2/CU exactly (LDS 2*33792+~600 = 68.2KB <= 80KB). launch_bounds(512,4) ->
// 128-VGPR cap; peak live ~90 regs, no spill expected.
// Per-component arithmetic is rounds 16/17 verbatim.
__global__ __launch_bounds__(BLOCK, 4) void qsim_kernel(
    const float* __restrict__ x, const h16* __restrict__ BmG,
    const float* __restrict__ wtabG, const float* __restrict__ head_b,
    float* __restrict__ out)   // (512,2), fully overwritten (direct store)
{
  extern __shared__ __align__(16) char sbuf[];   // 2 x 33792 B state buffers
  __shared__ float wtab[88];
  __shared__ float xc[NQ], xs[NQ];
  __shared__ float redbuf[16];

  const int t = threadIdx.x;
  const int b = blockIdx.x;     // one block = one batch item (both components)
  const int lane = t & 63;
  const int w = t >> 6;         // 8 waves
  const int m = lane & 15;
  const int kg = lane >> 4;

  char* const bufR = sbuf;          // real component state
  char* const bufI = sbuf + BUFSZ;  // imaginary component state

  // ---- phase 0: load tables / per-item trig ----
  if (t < 88) wtab[t] = wtabG[t];
  if (t >= 128 && t < 128 + NQ) {
    int bit = t - 128;
    float h = 0.5f * x[b * NQ + (13 - bit)];
    xc[bit] = cosf(h); xs[bit] = sinf(h);
  }
  __syncthreads();

  // ---- init product state, BOTH components (each amp nonzero in exactly one) ----
  {
    float Mt = 1.f;
    #pragma unroll
    for (int p = 5; p < 14; ++p) Mt *= ((t >> (p - 5)) & 1) ? xs[p] : xc[p];
    const int pct = __popc((unsigned)t);
    uint32_t base = (uint32_t)(t >> 3) * TS + (uint32_t)((2 * t) & 15) * 32;
    #pragma unroll
    for (int g = 0; g < 4; ++g) {
      union { h16 h[8]; uint4 u; } pkR, pkI;
      #pragma unroll
      for (int i = 0; i < 8; ++i) {
        int j = g * 8 + i;
        float mm = Mt;
        #pragma unroll
        for (int p = 0; p < 5; ++p) mm *= ((j >> p) & 1) ? xs[p] : xc[p];
        int e = (pct + __popc((unsigned)j)) & 3;   // (-i)^e
        pkR.h[i] = (h16)((e == 0) ? mm : ((e == 2) ? -mm : 0.f));
        pkI.h[i] = (h16)((e == 1) ? -mm : ((e == 3) ? mm : 0.f));
      }
      uint32_t off = base + (uint32_t)(g >> 1) * 32 + (uint32_t)(g & 1) * 16;
      *(uint4*)(bufR + off) = pkR.u;
      *(uint4*)(bufI + off) = pkI.u;
    }
  }
  __syncthreads();

  // A-fragment (16x16x16): lane reads row m, cols kg*4..kg*4+3 -> b64, ALL lanes
  const uint32_t raA = (uint32_t)w * (8 * TS) + (uint32_t)m * 32 + (uint32_t)kg * 8;
  const uint32_t raB = (uint32_t)((w & 1) * 8 + 16 * (w >> 1)) * TS
                     + (uint32_t)m * 32 + (uint32_t)kg * 8;
  const uint32_t wbase = (uint32_t)m * TS + ((uint32_t)(w >> 1) + 4u * (uint32_t)kg) * 32
                       + (uint32_t)((w & 1) * 16);

  float l0 = 0.f, l1 = 0.f;

  // paired half-layer for BOTH components between one barrier pair.
  auto do_half = [&](uint32_t rbase, h4 gB, h4 gA, bool last) {
    h4 avR[8], avI[8];
    #pragma unroll
    for (int jt = 0; jt < 8; ++jt)
      avR[jt] = *(const h4*)(bufR + rbase + (uint32_t)jt * TS);
    #pragma unroll
    for (int jt = 0; jt < 8; ++jt)
      avI[jt] = *(const h4*)(bufI + rbase + (uint32_t)jt * TS);
    uint32_t qkR[8][2], qkI[8][2];
    float bs0 = 0.f, bs1 = 0.f;
    if (last) {
      bs0 = wtab[32 + m] + wtab[64 + (w >> 1)] + wtab[72 + kg];
      bs1 = wtab[48 + m] + wtab[68 + (w >> 1)] + wtab[76 + kg];
    }
    __builtin_amdgcn_s_setprio(1);
    #pragma unroll
    for (int jt = 0; jt < 8; ++jt) {      // real component chains
      f4 acc = {0.f, 0.f, 0.f, 0.f};
      acc = __builtin_amdgcn_mfma_f32_16x16x16f16(avR[jt], gB, acc, 0, 0, 0);
      union { h16 h[4]; h4 v; } c1;
      c1.h[0] = (h16)acc[0]; c1.h[1] = (h16)acc[1];
      c1.h[2] = (h16)acc[2]; c1.h[3] = (h16)acc[3];
      f4 acc2 = {0.f, 0.f, 0.f, 0.f};
      acc2 = __builtin_amdgcn_mfma_f32_16x16x16f16(gA, c1.v, acc2, 0, 0, 0);
      if (!last) {
        union { h16 h[4]; uint32_t d[2]; } c2;
        c2.h[0] = (h16)acc2[0]; c2.h[1] = (h16)acc2[1];
        c2.h[2] = (h16)acc2[2]; c2.h[3] = (h16)acc2[3];
        qkR[jt][0] = c2.d[0]; qkR[jt][1] = c2.d[1];
      } else {
        float wt0 = wtab[(w & 1) * 8 + jt], wt1 = wtab[16 + (w & 1) * 8 + jt];
        #pragma unroll
        for (int j = 0; j < 4; ++j) {
          float pr = acc2[j] * acc2[j];
          l0 += pr * (bs0 + wt0 + wtab[80 + j]);
          l1 += pr * (bs1 + wt1 + wtab[84 + j]);
        }
      }
    }
    #pragma unroll
    for (int jt = 0; jt < 8; ++jt) {      // imaginary component chains
      f4 acc = {0.f, 0.f, 0.f, 0.f};
      acc = __builtin_amdgcn_mfma_f32_16x16x16f16(avI[jt], gB, acc, 0, 0, 0);
      union { h16 h[4]; h4 v; } c1;
      c1.h[0] = (h16)acc[0]; c1.h[1] = (h16)acc[1];
      c1.h[2] = (h16)acc[2]; c1.h[3] = (h16)acc[3];
      f4 acc2 = {0.f, 0.f, 0.f, 0.f};
      acc2 = __builtin_amdgcn_mfma_f32_16x16x16f16(gA, c1.v, acc2, 0, 0, 0);
      if (!last) {
        union { h16 h[4]; uint32_t d[2]; } c2;
        c2.h[0] = (h16)acc2[0]; c2.h[1] = (h16)acc2[1];
        c2.h[2] = (h16)acc2[2]; c2.h[3] = (h16)acc2[3];
        qkI[jt][0] = c2.d[0]; qkI[jt][1] = c2.d[1];
      } else {
        float wt0 = wtab[(w & 1) * 8 + jt], wt1 = wtab[16 + (w & 1) * 8 + jt];
        #pragma unroll
        for (int j = 0; j < 4; ++j) {
          float pr = acc2[j] * acc2[j];
          l0 += pr * (bs0 + wt0 + wtab[80 + j]);
          l1 += pr * (bs1 + wt1 + wtab[84 + j]);
        }
      }
    }
    __builtin_amdgcn_s_setprio(0);
    if (!last) {
      BAR_WAR();    // all waves' reads done (consumed pre-arrival); no vmcnt drain
      #pragma unroll
      for (int r = 0; r < 4; ++r) {
        uint32_t oR[4], oI[4];
        #pragma unroll
        for (int q = 0; q < 4; ++q) {
          uint32_t loR = qkR[2 * q][r >> 1], hiR = qkR[2 * q + 1][r >> 1];
          uint32_t loI = qkI[2 * q][r >> 1], hiI = qkI[2 * q + 1][r >> 1];
          oR[q] = (r & 1) ? __builtin_amdgcn_perm(hiR, loR, 0x07060302u)
                          : __builtin_amdgcn_perm(hiR, loR, 0x05040100u);
          oI[q] = (r & 1) ? __builtin_amdgcn_perm(hiI, loI, 0x07060302u)
                          : __builtin_amdgcn_perm(hiI, loI, 0x05040100u);
        }
        uint32_t wa = wbase + (uint32_t)r * (16 * TS);
        *(uint4*)(bufR + wa) = make_uint4(oR[0], oR[1], oR[2], oR[3]);
        *(uint4*)(bufI + wa) = make_uint4(oI[0], oI[1], oI[2], oI[3]);
      }
      BAR_PUB();    // drain LDS writes only (lgkmcnt), then barrier
    }
  };

  // gate fragments: per layer from d_ws (L2-hot broadcast, shared by both comps)
  const h16* fb = BmG + (m * 16 + kg * 4);

  #pragma unroll 1
  for (int d = 0; d < DEPTH; ++d) {
    const h16* nf = fb + d * 1024;
    h4 g0f = *(const h4*)(nf +   0);
    h4 g1f = *(const h4*)(nf + 256);
    h4 g2f = *(const h4*)(nf + 512);
    h4 g3f = *(const h4*)(nf + 768);
    do_half(raA, g0f, g1f, false);                 // passes 0,1 (g0 then g1)
    do_half(raB, g2f, g3f, d == DEPTH - 1);        // passes 2,3 (g2 then g3grp)
  }

  // ---- reduce logits (both comps already summed), direct store ----
  #pragma unroll
  for (int off = 32; off > 0; off >>= 1) {
    l0 += __shfl_xor(l0, off);
    l1 += __shfl_xor(l1, off);
  }
  if (lane == 0) { redbuf[w] = l0; redbuf[8 + w] = l1; }
  __syncthreads();
  if (t == 0) {
    float s0 = head_b[0], s1 = head_b[1];
    #pragma unroll
    for (int i = 0; i < 8; ++i) { s0 += redbuf[i]; s1 += redbuf[8 + i]; }
    out[b * 2 + 0] = s0;
    out[b * 2 + 1] = s1;
  }
}

extern "C" void kernel_launch(void* const* d_in, const int* in_sizes, int n_in,
                              void* d_out, int out_size, void* d_ws, size_t ws_size,
                              hipStream_t stream) {
    const float* x      = (const float*)d_in[0];
    const float* theta  = (const float*)d_in[1];
    const float* head_w = (const float*)d_in[2];
    const float* head_b = (const float*)d_in[3];
    float* outp = (float*)d_out;
    h16*  BmG   = (h16*)d_ws;
    float* wtabG = (float*)((char*)d_ws + 12288);
    const int batch = in_sizes[0] / NQ;  // 512
    prep_kernel<<<1, 512, 0, stream>>>(theta, head_w, BmG, wtabG);
    qsim_kernel<<<batch, BLOCK, 2 * BUFSZ, stream>>>(x, BmG, wtabG, head_b, outp);
}

// Round 19
// 51.630 us; speedup vs baseline: 1.0225x; 1.0225x over previous
//
#include <hip/hip_runtime.h>
#include <math.h>

#define NQ 14
#define DEPTH 6
#define BLOCK 512
#define TS 528u       // bytes per 16x16 f16 tile: 512 data + 16 pad (132 dwords = 4 mod 32)
#define BUFSZ 33792u  // 64 * TS

typedef _Float16 h16;
typedef h16 h4 __attribute__((ext_vector_type(4)));
typedef float f4 __attribute__((ext_vector_type(4)));

// WAR barrier: no waitcnt needed (all prior ds_reads already consumed by MFMA);
// crucially does NOT drain vmcnt -> per-layer global gate loads stay in flight.
#define BAR_WAR() asm volatile("s_barrier" ::: "memory")
// Publish barrier: drain LDS writes only (lgkmcnt), not vmcnt.
#define BAR_PUB() asm volatile("s_waitcnt lgkmcnt(0)\n\ts_barrier" ::: "memory")

// ============ pre-kernel: constants -> d_ws, plus out zeroing ============
// BmG[24][256] h16 at ws+0 (12288 B); wtab[88] float at ws+12288.
__global__ __launch_bounds__(512, 1) void prep_kernel(
    const float* __restrict__ theta, const float* __restrict__ head_w,
    h16* __restrict__ BmG, float* __restrict__ wtab, float* __restrict__ outp)
{
  __shared__ float2 gtab[DEPTH * NQ];
  const int t = threadIdx.x;
  if (t < 256)   // zero out[1024] (replaces a separate hipMemsetAsync dispatch)
    *(float4*)(outp + 4 * t) = make_float4(0.f, 0.f, 0.f, 0.f);
  if (t < DEPTH * NQ) {
    int d = t / NQ, bit = t - d * NQ;
    float hg = 0.5f * theta[d * NQ + (13 - bit)];
    gtab[t] = make_float2(cosf(hg), sinf(hg));
  }
  if (t < 88) {
    int o, v; float s = 0.f;
    if (t < 32) { o = t >> 4; v = t & 15;
      #pragma unroll
      for (int i = 0; i < 4; ++i) s += ((v>>i)&1) ? -head_w[o*NQ+i] : head_w[o*NQ+i];
    } else if (t < 64) { o = (t-32) >> 4; v = t & 15;
      #pragma unroll
      for (int i = 0; i < 4; ++i) s += ((v>>i)&1) ? -head_w[o*NQ+8+i] : head_w[o*NQ+8+i];
    } else if (t < 72) { o = (t-64) >> 2; v = t & 3;
      s = ((v&1)?-head_w[o*NQ+4]:head_w[o*NQ+4]) + ((v&2)?-head_w[o*NQ+5]:head_w[o*NQ+5]);
    } else if (t < 80) { o = (t-72) >> 2; v = t & 3;
      s = ((v&1)?-head_w[o*NQ+6]:head_w[o*NQ+6]) + ((v&2)?-head_w[o*NQ+7]:head_w[o*NQ+7]);
    } else { o = (t-80) >> 2; v = t & 3;
      s = ((v&1)?-head_w[o*NQ+12]:head_w[o*NQ+12]) + ((v&2)?-head_w[o*NQ+13]:head_w[o*NQ+13]);
    }
    wtab[t] = s;
  }
  __syncthreads();
  // Bm: 24 x 16 x 16 (arithmetic = rounds 5-18, CZ signs baked)
  #pragma unroll
  for (int i = 0; i < 12; ++i) {
    int e = t + (i << 9);
    int pid = e >> 8, n = (e >> 4) & 15, k = e & 15;
    int d = pid >> 2, p = pid & 3;
    float val;
    if (p < 3) {
      val = 1.f;
      #pragma unroll
      for (int j = 0; j < 4; ++j) {
        float2 g = gtab[d * NQ + 4 * p + j];
        val *= ((n >> j) & 1) ? (((k >> j) & 1) ? g.x : g.y)
                              : (((k >> j) & 1) ? -g.y : g.x);
      }
      if (d >= 1) {
        int s = ((k & (k >> 1)) ^ ((k >> 1) & (k >> 2)) ^ ((k >> 2) & (k >> 3))) & 1;
        if (s) val = -val;
        if ((n & 1) && (k & 8)) val = -val;    // cross-pair CZ sign
      }
    } else {          // g3grp = [12,13,6,7]: G12 x G13 x I x I
      if ((((n ^ k) >> 2) & 3) != 0) val = 0.f;
      else {
        float2 gA = gtab[d * NQ + 12], gB = gtab[d * NQ + 13];
        float f0 = (n & 1) ? ((k & 1) ? gA.x : gA.y) : ((k & 1) ? -gA.y : gA.x);
        float f1 = ((n >> 1) & 1) ? (((k >> 1) & 1) ? gB.x : gB.y)
                                  : (((k >> 1) & 1) ? -gB.y : gB.x);
        val = f0 * f1;
        if (d >= 1 && (k & (k >> 1) & 1)) val = -val;    // intra pair (12,13)
      }
    }
    BmG[pid * 256 + n * 16 + k] = (h16)val;
  }
}

// ============ main kernel ============
// One block = one real component (comp=blockIdx&1) of item b=blockIdx>>1.
// ROUND-19: revert to the round-16 best-measured configuration (fusion of r18
// falsified: -57%->35% occupancy cost > barrier savings). Single in-place
// buffer, LDS-staged init, paired x16-MFMA halves with D1->B2 register
// chaining, per-layer gates from d_ws, asm barriers, bit-exact v_perm merges.
// 4 blocks/CU (LDS ~34.4KB), 1024 blocks = 4/CU exactly, zero tail.
__global__ __launch_bounds__(BLOCK, 8) void qsim_kernel(
    const float* __restrict__ x, const h16* __restrict__ BmG,
    const float* __restrict__ wtabG, const float* __restrict__ head_b,
    float* __restrict__ out)   // (512,2) zeroed by prep, accumulated atomically
{
  extern __shared__ __align__(16) char sbuf[];   // 33792 B state buffer (in-place)
  __shared__ float wtab[88];
  __shared__ float xc[NQ], xs[NQ];
  __shared__ float redbuf[16];

  const int t = threadIdx.x;
  const int b = blockIdx.x >> 1;
  const int comp = blockIdx.x & 1;
  const int lane = t & 63;
  const int w = t >> 6;        // 8 waves
  const int m = lane & 15;
  const int kg = lane >> 4;

  // ---- phase 0: load tables / per-item trig ----
  if (t < 88) wtab[t] = wtabG[t];
  if (t >= 128 && t < 128 + NQ) {
    int bit = t - 128;
    float h = 0.5f * x[b * NQ + (13 - bit)];
    xc[bit] = cosf(h); xs[bit] = sinf(h);
  }
  __syncthreads();

  // ---- init product state -> view X (E0 ordering, rounds 7-18) ----
  {
    float Mt = 1.f;
    #pragma unroll
    for (int p = 5; p < 14; ++p) Mt *= ((t >> (p - 5)) & 1) ? xs[p] : xc[p];
    const int pct = __popc((unsigned)t);
    uint32_t base = (uint32_t)(t >> 3) * TS + (uint32_t)((2 * t) & 15) * 32;
    #pragma unroll
    for (int g = 0; g < 4; ++g) {
      union { h16 h[8]; uint4 u; } pk;
      #pragma unroll
      for (int i = 0; i < 8; ++i) {
        int j = g * 8 + i;
        float mm = Mt;
        #pragma unroll
        for (int p = 0; p < 5; ++p) mm *= ((j >> p) & 1) ? xs[p] : xc[p];
        int e = (pct + __popc((unsigned)j)) & 3;   // (-i)^e
        float v = (comp == 0) ? ((e == 0) ? mm : ((e == 2) ? -mm : 0.f))
                              : ((e == 1) ? -mm : ((e == 3) ? mm : 0.f));
        pk.h[i] = (h16)v;
      }
      *(uint4*)(sbuf + base + (uint32_t)(g >> 1) * 32 + (uint32_t)(g & 1) * 16) = pk.u;
    }
  }
  __syncthreads();

  // A-fragment (16x16x16): lane reads row m, cols kg*4..kg*4+3 -> b64, ALL lanes
  const uint32_t raA = (uint32_t)w * (8 * TS) + (uint32_t)m * 32 + (uint32_t)kg * 8;
  const uint32_t raB = (uint32_t)((w & 1) * 8 + 16 * (w >> 1)) * TS
                     + (uint32_t)m * 32 + (uint32_t)kg * 8;
  const uint32_t wbase = (uint32_t)m * TS + ((uint32_t)(w >> 1) + 4u * (uint32_t)kg) * 32
                       + (uint32_t)((w & 1) * 16);

  float l0 = 0.f, l1 = 0.f;

  // paired half-layer: read, MFMA1(state,gB) -> MFMA2(gA, D1-as-B), write in-place.
  auto do_half = [&](uint32_t rbase, h4 gB, h4 gA, bool last) {
    h4 av[8];
    #pragma unroll
    for (int jt = 0; jt < 8; ++jt)
      av[jt] = *(const h4*)(sbuf + rbase + (uint32_t)jt * TS);
    uint32_t qk[8][2];
    float bs0 = 0.f, bs1 = 0.f;
    if (last) {
      bs0 = wtab[32 + m] + wtab[64 + (w >> 1)] + wtab[72 + kg];
      bs1 = wtab[48 + m] + wtab[68 + (w >> 1)] + wtab[76 + kg];
    }
    #pragma unroll
    for (int jt = 0; jt < 8; ++jt) {
      f4 acc = {0.f, 0.f, 0.f, 0.f};
      acc = __builtin_amdgcn_mfma_f32_16x16x16f16(av[jt], gB, acc, 0, 0, 0);
      union { h16 h[4]; h4 v; } c1;
      c1.h[0] = (h16)acc[0]; c1.h[1] = (h16)acc[1];
      c1.h[2] = (h16)acc[2]; c1.h[3] = (h16)acc[3];
      f4 acc2 = {0.f, 0.f, 0.f, 0.f};
      acc2 = __builtin_amdgcn_mfma_f32_16x16x16f16(gA, c1.v, acc2, 0, 0, 0);
      if (!last) {
        union { h16 h[4]; uint32_t d[2]; } c2;
        c2.h[0] = (h16)acc2[0]; c2.h[1] = (h16)acc2[1];
        c2.h[2] = (h16)acc2[2]; c2.h[3] = (h16)acc2[3];
        qk[jt][0] = c2.d[0]; qk[jt][1] = c2.d[1];
      } else {
        float wt0 = wtab[(w & 1) * 8 + jt], wt1 = wtab[16 + (w & 1) * 8 + jt];
        #pragma unroll
        for (int j = 0; j < 4; ++j) {
          float pr = acc2[j] * acc2[j];
          l0 += pr * (bs0 + wt0 + wtab[80 + j]);
          l1 += pr * (bs1 + wt1 + wtab[84 + j]);
        }
      }
    }
    if (!last) {
      BAR_WAR();    // all waves' reads of this view done (consumed pre-arrival);
                    // no waitcnt -> global gate loads stay in flight
      #pragma unroll
      for (int r = 0; r < 4; ++r) {
        uint32_t o[4];
        #pragma unroll
        for (int q = 0; q < 4; ++q) {
          uint32_t lo = qk[2 * q][r >> 1], hi = qk[2 * q + 1][r >> 1];
          // bit-exact single-op merges: even r -> {lo0,lo1,hi0,hi1},
          // odd r -> {lo2,lo3,hi2,hi3}
          o[q] = (r & 1) ? __builtin_amdgcn_perm(hi, lo, 0x07060302u)
                         : __builtin_amdgcn_perm(hi, lo, 0x05040100u);
        }
        *(uint4*)(sbuf + wbase + (uint32_t)r * (16 * TS)) =
            make_uint4(o[0], o[1], o[2], o[3]);
      }
      BAR_PUB();    // drain LDS writes only (lgkmcnt), then barrier
    }
  };

  // gate fragments: loaded fresh at each layer top (L2-hot broadcast; short
  // live range -> no spill; loads overlap half-A compute thanks to BAR_WAR/PUB)
  const h16* fb = BmG + (m * 16 + kg * 4);

  #pragma unroll 1
  for (int d = 0; d < DEPTH; ++d) {
    const h16* nf = fb + d * 1024;
    h4 g0f = *(const h4*)(nf +   0);
    h4 g1f = *(const h4*)(nf + 256);
    h4 g2f = *(const h4*)(nf + 512);
    h4 g3f = *(const h4*)(nf + 768);
    do_half(raA, g0f, g1f, false);                 // passes 0,1 (g0 then g1)
    do_half(raB, g2f, g3f, d == DEPTH - 1);        // passes 2,3 (g2 then g3grp)
  }

  // ---- reduce partial logits, accumulate re/im via atomics ----
  #pragma unroll
  for (int off = 32; off > 0; off >>= 1) {
    l0 += __shfl_xor(l0, off);
    l1 += __shfl_xor(l1, off);
  }
  if (lane == 0) { redbuf[w] = l0; redbuf[8 + w] = l1; }
  __syncthreads();
  if (t == 0) {
    float s0 = 0.f, s1 = 0.f;
    #pragma unroll
    for (int i = 0; i < 8; ++i) { s0 += redbuf[i]; s1 += redbuf[8 + i]; }
    if (comp == 0) { s0 += head_b[0]; s1 += head_b[1]; }
    atomicAdd(&out[b * 2 + 0], s0);
    atomicAdd(&out[b * 2 + 1], s1);
  }
}

extern "C" void kernel_launch(void* const* d_in, const int* in_sizes, int n_in,
                              void* d_out, int out_size, void* d_ws, size_t ws_size,
                              hipStream_t stream) {
    const float* x      = (const float*)d_in[0];
    const float* theta  = (const float*)d_in[1];
    const float* head_w = (const float*)d_in[2];
    const float* head_b = (const float*)d_in[3];
    float* outp = (float*)d_out;
    h16*  BmG   = (h16*)d_ws;
    float* wtabG = (float*)((char*)d_ws + 12288);
    const int batch = in_sizes[0] / NQ;  // 512
    prep_kernel<<<1, 512, 0, stream>>>(theta, head_w, BmG, wtabG, outp);
    qsim_kernel<<<batch * 2, BLOCK, BUFSZ, stream>>>(x, BmG, wtabG, head_b, outp);
}